// Round 1
// baseline (38.135 us; speedup 1.0000x reference)
//
#include <hip/hip_runtime.h>

// RandomForest: out = mean_t(x @ W[t] + b[t]) = x @ mean_t(W) + mean_t(b)
// x: [65536,128] f32, W: [64,128,32] f32, b: [64,32] f32, out: [65536,32] f32

#define T_ 64
#define F_ 128
#define C_ 32
#define B_ 65536

// ---------------- kernel 1: average W and b over trees into d_ws ----------------
// ws[0..4095]   = W_avg[128][32]
// ws[4096..4127]= b_avg[32]
__global__ void avg_wb_kernel(const float* __restrict__ W,
                              const float* __restrict__ b,
                              float* __restrict__ ws) {
    int gid = blockIdx.x * blockDim.x + threadIdx.x;
    if (gid < F_ * C_) {
        float s = 0.f;
#pragma unroll
        for (int t = 0; t < T_; ++t) s += W[t * (F_ * C_) + gid];
        ws[gid] = s * (1.0f / T_);
    } else if (gid < F_ * C_ + C_) {
        int c = gid - F_ * C_;
        float s = 0.f;
#pragma unroll
        for (int t = 0; t < T_; ++t) s += b[t * C_ + c];
        ws[gid] = s * (1.0f / T_);
    }
}

// ---------------- kernel 2: out = x @ W_avg + b_avg ----------------
// block = 256 threads (4 waves), 128 rows per block, grid = 512.
// thread: col = tid&7 -> classes c0..c0+3 ; rthr = tid>>3 (0..31) -> rows rthr+{0,32,64,96}
// LDS: x chunk [128][68] (pad 4 -> conflict-free), W_avg [128][32] (full-row broadcast reads)
#define ROWS_PB 128
#define FCHUNK 64
#define XS 68
#define BLK 256

__global__ __launch_bounds__(BLK, 2) void forest_gemm(const float* __restrict__ x,
                                                      const float* __restrict__ ws,
                                                      float* __restrict__ out) {
    __shared__ __align__(16) float xs[ROWS_PB * XS];   // 34816 B
    __shared__ __align__(16) float wsh[F_ * C_];       // 16384 B

    const int tid  = threadIdx.x;
    const int row0 = blockIdx.x * ROWS_PB;
    const int c0   = (tid & 7) * 4;
    const int rthr = tid >> 3;

    // stage W_avg into LDS: 1024 float4, 4 per thread, coalesced
    {
        const float4* src = (const float4*)ws;
        float4* dst = (float4*)wsh;
#pragma unroll
        for (int i = 0; i < 4; ++i) dst[tid + BLK * i] = src[tid + BLK * i];
    }

    // bias (tiny broadcast read from global; no sync needed)
    float4 bias = *(const float4*)(ws + F_ * C_ + c0);

    float acc[4][4];
#pragma unroll
    for (int k = 0; k < 4; ++k) {
        acc[k][0] = bias.x; acc[k][1] = bias.y; acc[k][2] = bias.z; acc[k][3] = bias.w;
    }

#pragma unroll
    for (int ch = 0; ch < F_ / FCHUNK; ++ch) {
        const int f0 = ch * FCHUNK;
        if (ch) __syncthreads();  // protect xs against overwrite of previous chunk
        // stage x chunk: 128 rows x 64 feats = 2048 float4, 8 per thread, coalesced
#pragma unroll
        for (int i = 0; i < 8; ++i) {
            int idx = tid + BLK * i;          // 0..2047
            int row = idx >> 4;               // 0..127
            int fo  = (idx & 15) << 2;        // 0,4,...,60
            float4 v = *(const float4*)(x + (size_t)(row0 + row) * F_ + f0 + fo);
            *(float4*)&xs[row * XS + fo] = v;
        }
        __syncthreads();

#pragma unroll 4
        for (int fq = 0; fq < FCHUNK; fq += 4) {
            float4 w0 = *(const float4*)&wsh[(f0 + fq + 0) * C_ + c0];
            float4 w1 = *(const float4*)&wsh[(f0 + fq + 1) * C_ + c0];
            float4 w2 = *(const float4*)&wsh[(f0 + fq + 2) * C_ + c0];
            float4 w3 = *(const float4*)&wsh[(f0 + fq + 3) * C_ + c0];
#pragma unroll
            for (int k = 0; k < 4; ++k) {
                float4 xv = *(const float4*)&xs[(rthr + k * 32) * XS + fq];
                acc[k][0] += xv.x * w0.x; acc[k][0] += xv.y * w1.x;
                acc[k][0] += xv.z * w2.x; acc[k][0] += xv.w * w3.x;
                acc[k][1] += xv.x * w0.y; acc[k][1] += xv.y * w1.y;
                acc[k][1] += xv.z * w2.y; acc[k][1] += xv.w * w3.y;
                acc[k][2] += xv.x * w0.z; acc[k][2] += xv.y * w1.z;
                acc[k][2] += xv.z * w2.z; acc[k][2] += xv.w * w3.z;
                acc[k][3] += xv.x * w0.w; acc[k][3] += xv.y * w1.w;
                acc[k][3] += xv.z * w2.w; acc[k][3] += xv.w * w3.w;
            }
        }
    }

#pragma unroll
    for (int k = 0; k < 4; ++k) {
        int r = row0 + rthr + k * 32;
        *(float4*)&out[(size_t)r * C_ + c0] =
            make_float4(acc[k][0], acc[k][1], acc[k][2], acc[k][3]);
    }
}

extern "C" void kernel_launch(void* const* d_in, const int* in_sizes, int n_in,
                              void* d_out, int out_size, void* d_ws, size_t ws_size,
                              hipStream_t stream) {
    const float* x = (const float*)d_in[0];   // logits [65536,128]
    const float* W = (const float*)d_in[1];   // [64,128,32]
    const float* b = (const float*)d_in[2];   // [64,32]
    float* out = (float*)d_out;               // [65536,32]
    float* ws  = (float*)d_ws;                // >= 4128 floats

    avg_wb_kernel<<<(F_ * C_ + C_ + 255) / 256, 256, 0, stream>>>(W, b, ws);
    forest_gemm<<<B_ / ROWS_PB, BLK, 0, stream>>>(x, ws, out);
}

// Round 2
// 21.970 us; speedup vs baseline: 1.7357x; 1.7357x over previous
//
#include <hip/hip_runtime.h>

// RandomForest: out = mean_t(x @ W[t] + b[t]) = x @ mean_t(W) + mean_t(b)
// x: [65536,128] f32, W: [64,128,32] f32, b: [64,32] f32, out: [65536,32] f32

#define T_ 64
#define F_ 128
#define C_ 32
#define B_ 65536

// ---------------- kernel 1: average W and b over trees into d_ws (float4) ----
// ws[0..4095]    = W_avg[128][32]
// ws[4096..4127] = b_avg[32]
__global__ void avg_wb_kernel(const float4* __restrict__ W4,
                              const float4* __restrict__ b4,
                              float4* __restrict__ ws4) {
    int gid = blockIdx.x * blockDim.x + threadIdx.x;
    const float s = 1.0f / T_;
    if (gid < F_ * C_ / 4) {
        float4 a = make_float4(0.f, 0.f, 0.f, 0.f);
#pragma unroll
        for (int t = 0; t < T_; ++t) {
            float4 v = W4[t * (F_ * C_ / 4) + gid];
            a.x += v.x; a.y += v.y; a.z += v.z; a.w += v.w;
        }
        ws4[gid] = make_float4(a.x * s, a.y * s, a.z * s, a.w * s);
    } else if (gid < F_ * C_ / 4 + C_ / 4) {
        int c = gid - F_ * C_ / 4;
        float4 a = make_float4(0.f, 0.f, 0.f, 0.f);
#pragma unroll
        for (int t = 0; t < T_; ++t) {
            float4 v = b4[t * (C_ / 4) + c];
            a.x += v.x; a.y += v.y; a.z += v.z; a.w += v.w;
        }
        ws4[F_ * C_ / 4 + c] = make_float4(a.x * s, a.y * s, a.z * s, a.w * s);
    }
}

// ---------------- kernel 2: out = x @ W_avg + b_avg ----------------
// 1024 blocks x 256 threads; 64 rows/block. LDS 49 KB -> 3 blocks/CU (12 waves/CU).
// ONE barrier per block: stage x-tile + W, sync, then pure register compute.
// thread: c0 = (tid&7)*4 (8 col groups), rthr = tid>>3 -> rows rthr, rthr+32.
#define ROWS_PB 64
#define XS 132          // 128 + 4 pad floats; x-read start bank = 4*rthr -> conflict-free
#define BLK 256

__global__ __launch_bounds__(BLK, 3) void forest_gemm(const float* __restrict__ x,
                                                      const float* __restrict__ ws,
                                                      float* __restrict__ out) {
    __shared__ __align__(16) float xs[ROWS_PB * XS];   // 33792 B
    __shared__ __align__(16) float wsh[F_ * C_];       // 16384 B

    const int tid  = threadIdx.x;
    const int row0 = blockIdx.x * ROWS_PB;
    const int c0   = (tid & 7) * 4;
    const int rthr = tid >> 3;

    // stage W_avg: 1024 float4, 4 per thread, coalesced
    {
        const float4* src = (const float4*)ws;
        float4* dst = (float4*)wsh;
#pragma unroll
        for (int i = 0; i < 4; ++i) dst[tid + BLK * i] = src[tid + BLK * i];
    }

    // stage x tile: 64 rows x 128 f = 2048 float4, 8 per thread, coalesced
#pragma unroll
    for (int i = 0; i < 8; ++i) {
        int idx = tid + BLK * i;          // 0..2047
        int row = idx >> 5;               // 0..63
        int f4  = idx & 31;               // 0..31
        float4 v = *(const float4*)(x + (size_t)(row0 + row) * F_ + f4 * 4);
        *(float4*)&xs[row * XS + f4 * 4] = v;
    }

    float4 bias = *(const float4*)(ws + F_ * C_ + c0);
    float acc0[4] = {bias.x, bias.y, bias.z, bias.w};
    float acc1[4] = {bias.x, bias.y, bias.z, bias.w};

    __syncthreads();   // the only barrier

    const float* xr0 = &xs[rthr * XS];
    const float* xr1 = &xs[(rthr + 32) * XS];
    const float* wp  = &wsh[c0];

#pragma unroll 8
    for (int f = 0; f < F_; f += 4) {
        float4 w0 = *(const float4*)&wp[(f + 0) * C_];
        float4 w1 = *(const float4*)&wp[(f + 1) * C_];
        float4 w2 = *(const float4*)&wp[(f + 2) * C_];
        float4 w3 = *(const float4*)&wp[(f + 3) * C_];
        float4 xa = *(const float4*)&xr0[f];
        float4 xb = *(const float4*)&xr1[f];

        acc0[0] += xa.x * w0.x; acc0[0] += xa.y * w1.x;
        acc0[0] += xa.z * w2.x; acc0[0] += xa.w * w3.x;
        acc0[1] += xa.x * w0.y; acc0[1] += xa.y * w1.y;
        acc0[1] += xa.z * w2.y; acc0[1] += xa.w * w3.y;
        acc0[2] += xa.x * w0.z; acc0[2] += xa.y * w1.z;
        acc0[2] += xa.z * w2.z; acc0[2] += xa.w * w3.z;
        acc0[3] += xa.x * w0.w; acc0[3] += xa.y * w1.w;
        acc0[3] += xa.z * w2.w; acc0[3] += xa.w * w3.w;

        acc1[0] += xb.x * w0.x; acc1[0] += xb.y * w1.x;
        acc1[0] += xb.z * w2.x; acc1[0] += xb.w * w3.x;
        acc1[1] += xb.x * w0.y; acc1[1] += xb.y * w1.y;
        acc1[1] += xb.z * w2.y; acc1[1] += xb.w * w3.y;
        acc1[2] += xb.x * w0.z; acc1[2] += xb.y * w1.z;
        acc1[2] += xb.z * w2.z; acc1[2] += xb.w * w3.z;
        acc1[3] += xb.x * w0.w; acc1[3] += xb.y * w1.w;
        acc1[3] += xb.z * w2.w; acc1[3] += xb.w * w3.w;
    }

    *(float4*)&out[(size_t)(row0 + rthr) * C_ + c0] =
        make_float4(acc0[0], acc0[1], acc0[2], acc0[3]);
    *(float4*)&out[(size_t)(row0 + rthr + 32) * C_ + c0] =
        make_float4(acc1[0], acc1[1], acc1[2], acc1[3]);
}

extern "C" void kernel_launch(void* const* d_in, const int* in_sizes, int n_in,
                              void* d_out, int out_size, void* d_ws, size_t ws_size,
                              hipStream_t stream) {
    const float* x = (const float*)d_in[0];   // logits [65536,128]
    const float* W = (const float*)d_in[1];   // [64,128,32]
    const float* b = (const float*)d_in[2];   // [64,32]
    float* out = (float*)d_out;               // [65536,32]
    float* ws  = (float*)d_ws;                // >= 4128 floats

    avg_wb_kernel<<<5, 256, 0, stream>>>((const float4*)W, (const float4*)b, (float4*)ws);
    forest_gemm<<<B_ / ROWS_PB, BLK, 0, stream>>>(x, ws, out);
}

// Round 3
// 17.309 us; speedup vs baseline: 2.2032x; 1.2693x over previous
//
#include <hip/hip_runtime.h>

// RandomForest: out = mean_t(x @ W[t] + b[t]) = x @ mean_t(W) + mean_t(b)
// x: [65536,128] f32, W: [64,128,32] f32, b: [64,32] f32, out: [65536,32] f32
//
// Path: prep kernel builds W_avg as bf16 hi/lo MFMA B-fragments + b_avg (f32);
// GEMM kernel does x(bf16 hi/lo split) @ W via 3-product compensated
// mfma_f32_16x16x32_bf16. Accuracy ~1e-3 (fp32-assoc level), threshold 7.5e-3.

#define T_ 64
#define F_ 128
#define C_ 32
#define B_ 65536

typedef short short8 __attribute__((ext_vector_type(8)));   // 8 bf16 = 4 VGPR
typedef float f32x4 __attribute__((ext_vector_type(4)));

__device__ __forceinline__ unsigned short bf16_rne(float f) {
    union { float f; unsigned int u; } v; v.f = f;
    unsigned int r = (v.u + 0x7FFFu + ((v.u >> 16) & 1u)) >> 16;  // RNE, no NaN in data
    return (unsigned short)r;
}
__device__ __forceinline__ float bf16_tof(unsigned short h) {
    union { unsigned int u; float f; } v; v.u = ((unsigned int)h) << 16;
    return v.f;
}

// ws byte layout:
//   [0     .. 8191 ]  B_hi frags: ((nt*4+ks)*64 + lane)*16 + j*2   (ushort bf16)
//   [8192  .. 16383]  B_lo frags, same indexing
//   [16384 .. 16511]  b_avg f32[32]

// ---------------- kernel 1: average W,b -> bf16 hi/lo B-fragments ------------
// 64 blocks x 256 threads. Block bo covers 64 (f,c) outputs; 4 wave-groups
// each sum 16 trees (coalesced 256B runs), LDS-reduce, q==0 writes frags.
__global__ __launch_bounds__(256) void prep_kernel(const float* __restrict__ W,
                                                   const float* __restrict__ bv,
                                                   unsigned char* __restrict__ ws) {
    __shared__ float red[256];
    const int t = threadIdx.x;
    const int o = t & 63;
    const int q = t >> 6;
    const int gid = blockIdx.x * 64 + o;          // 0..4095  (f = gid>>5, c = gid&31)
    float s = 0.f;
#pragma unroll
    for (int i = 0; i < 16; ++i) s += W[(q * 16 + i) * (F_ * C_) + gid];
    red[t] = s;
    __syncthreads();
    if (q == 0) {
        float a = (s + red[o + 64] + red[o + 128] + red[o + 192]) * (1.0f / T_);
        unsigned short hi = bf16_rne(a);
        unsigned short lo = bf16_rne(a - bf16_tof(hi));
        int f = gid >> 5, c = gid & 31;
        // B[k=f][n=c] -> frag(nt,ks), lane = 16*g + (c&15), reg j ; k' = 8g + j
        int nt = c >> 4, ks = f >> 5, g = (f >> 3) & 3, j = f & 7;
        unsigned int off = (unsigned int)((nt * 4 + ks) * 64 + (g * 16 + (c & 15))) * 16u
                         + (unsigned int)j * 2u;
        *(unsigned short*)(ws + off) = hi;
        *(unsigned short*)(ws + 8192 + off) = lo;
    }
    if (blockIdx.x == 0 && t < C_) {
        float s2 = 0.f;
#pragma unroll
        for (int tt = 0; tt < T_; ++tt) s2 += bv[tt * C_ + t];
        *(float*)(ws + 16384 + t * 4) = s2 * (1.0f / T_);
    }
}

// ---------------- kernel 2: out = x @ W_avg + b_avg via MFMA -----------------
// 2048 blocks x 128 threads (2 waves); 32 rows/block; LDS 16 KB -> 8 blocks/CU
// fully resident (2048 = 256 CU x 8), no tail. One barrier per block.
#define GBLK 128
#define GROWS 32

__global__ __launch_bounds__(GBLK, 4) void forest_mfma(const float* __restrict__ x,
                                                       const unsigned char* __restrict__ ws,
                                                       float* __restrict__ out) {
    // per wave: A_hi[16][128] bf16 (4 KB, XOR-swizzled) + A_lo (4 KB)
    __shared__ __align__(16) unsigned char lds[16384];
    const int t   = threadIdx.x;
    const int l   = t & 63;
    const int wv  = t >> 6;
    const int row0 = blockIdx.x * GROWS;

    // 1) issue x tile loads: 32 rows x 128 f, 8 float4/thread, coalesced
    float4 xv[8];
#pragma unroll
    for (int i = 0; i < 8; ++i) {
        int idx = t + GBLK * i;                   // 0..1023
        int row = idx >> 5, c4 = idx & 31;
        xv[i] = *(const float4*)(x + (size_t)(row0 + row) * F_ + c4 * 4);
    }

    // 2) B fragments (held in regs whole kernel; L1/L2-resident) + bias
    const uint4* Bq = (const uint4*)ws;           // 512 hi frag-quads, then 512 lo
    short8 bh[2][4], bl[2][4];
#pragma unroll
    for (int nt = 0; nt < 2; ++nt)
#pragma unroll
        for (int ks = 0; ks < 4; ++ks) {
            uint4 vh = Bq[(nt * 4 + ks) * 64 + l];
            uint4 vl = Bq[512 + (nt * 4 + ks) * 64 + l];
            bh[nt][ks] = *(short8*)&vh;
            bl[nt][ks] = *(short8*)&vl;
        }
    const float* bias = (const float*)(ws + 16384);
    const int col = l & 15;
    const int g   = l >> 4;
    const float b0 = bias[col], b1 = bias[16 + col];

    // 3) convert fp32 -> bf16 hi/lo, store swizzled into this-row's wave region
#pragma unroll
    for (int i = 0; i < 8; ++i) {
        int idx = t + GBLK * i;
        int row = idx >> 5, c4 = idx & 31;
        int r = row & 15;
        unsigned int wb  = (unsigned int)(row >> 4) * 8192u;
        unsigned int off = wb + (unsigned int)r * 256u
                         + (((unsigned int)c4 * 8u) ^ ((unsigned int)(r & 7) << 4));
        unsigned short h0 = bf16_rne(xv[i].x), h1 = bf16_rne(xv[i].y),
                       h2 = bf16_rne(xv[i].z), h3 = bf16_rne(xv[i].w);
        unsigned short l0 = bf16_rne(xv[i].x - bf16_tof(h0)),
                       l1 = bf16_rne(xv[i].y - bf16_tof(h1)),
                       l2 = bf16_rne(xv[i].z - bf16_tof(h2)),
                       l3 = bf16_rne(xv[i].w - bf16_tof(h3));
        uint2 hw, lw;
        hw.x = (unsigned int)h0 | ((unsigned int)h1 << 16);
        hw.y = (unsigned int)h2 | ((unsigned int)h3 << 16);
        lw.x = (unsigned int)l0 | ((unsigned int)l1 << 16);
        lw.y = (unsigned int)l2 | ((unsigned int)l3 << 16);
        *(uint2*)(lds + off)        = hw;
        *(uint2*)(lds + 4096 + off) = lw;
    }
    __syncthreads();   // the only barrier

    // 4) 24 MFMAs: 2 N-tiles x 4 K-steps x 3 compensated products
    f32x4 acc0 = {b0, b0, b0, b0};
    f32x4 acc1 = {b1, b1, b1, b1};
    const unsigned int abase = (unsigned int)wv * 8192u;
#pragma unroll
    for (int ks = 0; ks < 4; ++ks) {
        unsigned int roff = abase + (unsigned int)col * 256u
            + ((((unsigned int)ks * 64u) + ((unsigned int)g * 16u))
               ^ ((unsigned int)(col & 7) << 4));
        uint4 vh = *(const uint4*)(lds + roff);
        uint4 vl = *(const uint4*)(lds + 4096 + roff);
        short8 ah = *(short8*)&vh;
        short8 al = *(short8*)&vl;
        acc0 = __builtin_amdgcn_mfma_f32_16x16x32_bf16(ah, bh[0][ks], acc0, 0, 0, 0);
        acc0 = __builtin_amdgcn_mfma_f32_16x16x32_bf16(ah, bl[0][ks], acc0, 0, 0, 0);
        acc0 = __builtin_amdgcn_mfma_f32_16x16x32_bf16(al, bh[0][ks], acc0, 0, 0, 0);
        acc1 = __builtin_amdgcn_mfma_f32_16x16x32_bf16(ah, bh[1][ks], acc1, 0, 0, 0);
        acc1 = __builtin_amdgcn_mfma_f32_16x16x32_bf16(ah, bl[1][ks], acc1, 0, 0, 0);
        acc1 = __builtin_amdgcn_mfma_f32_16x16x32_bf16(al, bh[1][ks], acc1, 0, 0, 0);
    }

    // 5) epilogue: C/D layout (verified m89): col = lane&15, row = 4*(lane>>4)+r
    const int orow = row0 + wv * 16 + 4 * g;
#pragma unroll
    for (int r = 0; r < 4; ++r) {
        out[(size_t)(orow + r) * C_ + col]      = acc0[r];
        out[(size_t)(orow + r) * C_ + 16 + col] = acc1[r];
    }
}

extern "C" void kernel_launch(void* const* d_in, const int* in_sizes, int n_in,
                              void* d_out, int out_size, void* d_ws, size_t ws_size,
                              hipStream_t stream) {
    const float* x = (const float*)d_in[0];   // logits [65536,128]
    const float* W = (const float*)d_in[1];   // [64,128,32]
    const float* b = (const float*)d_in[2];   // [64,32]
    float* out = (float*)d_out;               // [65536,32]
    unsigned char* ws = (unsigned char*)d_ws; // uses 16.5 KB

    prep_kernel<<<64, 256, 0, stream>>>(W, b, ws);
    forest_mfma<<<B_ / GROWS, GBLK, 0, stream>>>(x, ws, out);
}